// Round 1
// baseline (12.011 us; speedup 1.0000x reference)
//
#include <hip/hip_runtime.h>
#include <math.h>

// Problem constants (reference: B=16, C=3, H=W=512, N_BINS=100)
#define HDIM   512
#define WDIM   512
#define BATCH  16
#define NBINS  100
#define NPIX   (HDIM * WDIM)

// max_radius = sqrt(512^2 + 512^2)/2 = 256*sqrt(2); step = max_radius/100
#define STEP      3.6203867196751236f
#define INV_STEP  0.27621358640099516f
#define CUT       13.0f   // sigmoid(+-13) within 2.3e-6 of {1,0}

__global__ __launch_bounds__(256) void fq_mask_kernel(
    const float* __restrict__ value_set,  // [16][100]
    float* __restrict__ out_mask,         // [16][512][512]
    float* __restrict__ out_vs)           // [16][100] passthrough
{
    __shared__ float vs[BATCH * NBINS];
    const int tid = threadIdx.x;
    #pragma unroll
    for (int i = tid; i < BATCH * NBINS; i += 256) vs[i] = value_set[i];
    __syncthreads();

    const int pix = blockIdx.x * 256 + tid;   // 0 .. 262143
    const int h = pix >> 9;                   // row
    const int w = pix & (WDIM - 1);           // col

    const float dy = (float)h - (float)(HDIM / 2);
    const float dx = (float)w - (float)(WDIM / 2);
    const float dist = sqrtf(dy * dy + dx * dx);

    // Active bin window: bins with |step*(r+1) - dist| <= CUT.
    // Outside it sigmoid saturates; the telescoped mask contribution is <=
    // ~sigmoid(-CUT) ~ 2.3e-6 of max|value| on each side.
    int r_lo = (int)floorf((dist - CUT) * INV_STEP);
    if (r_lo < 0) r_lo = 0;
    int r_hi = (int)floorf((dist + CUT) * INV_STEP);
    if (r_hi > NBINS - 1) r_hi = NBINS - 1;

    float acc[BATCH];
    #pragma unroll
    for (int b = 0; b < BATCH; ++b) acc[b] = 0.0f;

    float s_prev = 0.0f;  // s_{r_lo - 1} ~ 0 (saturated)
    for (int r = r_lo; r <= r_hi; ++r) {
        float xr = STEP * (float)(r + 1) - dist;
        float e  = __expf(-xr);
        float s  = __fdividef(1.0f, 1.0f + e);  // sigmoid
        float m  = s - s_prev;                  // soft-histogram mask for bin r
        s_prev = s;
        #pragma unroll
        for (int b = 0; b < BATCH; ++b)
            acc[b] = fmaf(vs[b * NBINS + r], m, acc[b]);
    }

    #pragma unroll
    for (int b = 0; b < BATCH; ++b)
        out_mask[b * NPIX + pix] = acc[b];

    // Output 1: value_set passthrough (d_out is poisoned -> must write).
    if (blockIdx.x == 0) {
        #pragma unroll
        for (int i = tid; i < BATCH * NBINS; i += 256) out_vs[i] = vs[i];
    }
}

extern "C" void kernel_launch(void* const* d_in, const int* in_sizes, int n_in,
                              void* d_out, int out_size, void* d_ws, size_t ws_size,
                              hipStream_t stream) {
    // d_in[0] = x [16,3,512,512] fp32 — UNUSED by the math (shape-only).
    const float* value_set = (const float*)d_in[1];   // [16,100] fp32
    float* out_mask = (float*)d_out;                  // [16,512,512]
    float* out_vs   = (float*)d_out + BATCH * NPIX;   // [16,100]

    const int threads = 256;
    const int blocks  = NPIX / threads;  // 1024
    fq_mask_kernel<<<blocks, threads, 0, stream>>>(value_set, out_mask, out_vs);
}

// Round 3
// 11.811 us; speedup vs baseline: 1.0169x; 1.0169x over previous
//
#include <hip/hip_runtime.h>
#include <math.h>

// Problem constants (reference: B=16, C=3, H=W=512, N_BINS=100)
#define HDIM   512
#define WDIM   512
#define BATCH  16
#define NBINS  100
#define NPIX   (HDIM * WDIM)

// max_radius = sqrt(512^2+512^2)/2 = 256*sqrt(2); step = max_radius/100
#define STEP      3.6203867196751236f
#define INV_STEP  0.27621358640099516f
#define CUT       8.0f      // sigmoid(-8)=3.35e-4; truncation err <= ~7e-4 << 2e-2
#define VSTRIDE   20        // bin-row stride in floats: 80B (16B-aligned, spreads banks)

__device__ __forceinline__ float4 fma4(float a, float4 m, float4 c) {
    c.x = fmaf(a, m.x, c.x);
    c.y = fmaf(a, m.y, c.y);
    c.z = fmaf(a, m.z, c.z);
    c.w = fmaf(a, m.w, c.w);
    return c;
}

__global__ __launch_bounds__(256) void fq_mask_kernel(
    const float* __restrict__ value_set,  // [16][100]
    float* __restrict__ out_mask,         // [16][512][512]
    float* __restrict__ out_vs)           // [16][100] passthrough
{
    __shared__ __align__(16) float vst[NBINS * VSTRIDE];  // transposed: vst[r][b]
    const int tid = threadIdx.x;
    for (int i = tid; i < BATCH * NBINS; i += 256) {
        int b = i / NBINS;
        int r = i - b * NBINS;
        vst[r * VSTRIDE + b] = value_set[i];
    }
    __syncthreads();

    // Block tile 32x32 px; wave = 8 rows x 32 cols; thread = 4 consecutive cols.
    // Per-row store segment = 8 lanes x 16B = 128B full line, aligned.
    const int lane   = tid & 63;
    const int wv     = tid >> 6;
    const int row_in = wv * 8 + (lane >> 3);
    const int col_in = (lane & 7) * 4;
    const int by = blockIdx.x >> 4;
    const int bx = blockIdx.x & 15;
    const int h  = by * 32 + row_in;
    const int w  = bx * 32 + col_in;

    const float fy  = (float)h - 256.0f;
    const float dy2 = fy * fy;
    float d[4];
    #pragma unroll
    for (int p = 0; p < 4; ++p) {
        float dx = (float)(w + p) - 256.0f;
        d[p] = sqrtf(dy2 + dx * dx);
    }
    const float dmin = fminf(fminf(d[0], d[1]), fminf(d[2], d[3]));
    const float dmax = fmaxf(fmaxf(d[0], d[1]), fmaxf(d[2], d[3]));
    int r_lo = (int)floorf((dmin - CUT) * INV_STEP); if (r_lo < 0) r_lo = 0;
    int r_hi = (int)floorf((dmax + CUT) * INV_STEP); if (r_hi > NBINS - 1) r_hi = NBINS - 1;
    const int cnt = r_hi - r_lo + 1;   // ~5-6 iterations

    // e_p = exp(dist_p - STEP*(r+1)); per bin: s = 1/(1+e), then e *= exp(-STEP).
    const float dec = __expf(-STEP);
    float e[4], sp[4];
    #pragma unroll
    for (int p = 0; p < 4; ++p) {
        e[p]  = __expf(d[p] - STEP * (float)(r_lo + 1));
        sp[p] = 0.0f;   // matches reference: mask 0 = s[0] - 0
    }

    float4 acc[BATCH];
    #pragma unroll
    for (int b = 0; b < BATCH; ++b) acc[b] = make_float4(0.f, 0.f, 0.f, 0.f);

    int r = r_lo;
    for (int i = 0; i < cnt; ++i, ++r) {
        float mm[4];
        #pragma unroll
        for (int p = 0; p < 4; ++p) {
            float s = __builtin_amdgcn_rcpf(1.0f + e[p]);  // sigmoid
            mm[p]  = s - sp[p];
            sp[p]  = s;
            e[p]  *= dec;
        }
        const float4 m = make_float4(mm[0], mm[1], mm[2], mm[3]);
        const float4* vr = (const float4*)&vst[r * VSTRIDE];
        #pragma unroll
        for (int c = 0; c < 4; ++c) {
            float4 v = vr[c];
            acc[4*c + 0] = fma4(v.x, m, acc[4*c + 0]);
            acc[4*c + 1] = fma4(v.y, m, acc[4*c + 1]);
            acc[4*c + 2] = fma4(v.z, m, acc[4*c + 2]);
            acc[4*c + 3] = fma4(v.w, m, acc[4*c + 3]);
        }
    }

    const int pixbase = h * WDIM + w;
    #pragma unroll
    for (int b = 0; b < BATCH; ++b)
        *(float4*)&out_mask[b * NPIX + pixbase] = acc[b];

    // Output 1: value_set passthrough (d_out is poisoned -> must write).
    if (blockIdx.x == 0) {
        for (int i = tid; i < BATCH * NBINS; i += 256)
            out_vs[i] = value_set[i];
    }
}

extern "C" void kernel_launch(void* const* d_in, const int* in_sizes, int n_in,
                              void* d_out, int out_size, void* d_ws, size_t ws_size,
                              hipStream_t stream) {
    // d_in[0] = x [16,3,512,512] fp32 — UNUSED by the math (shape-only).
    const float* value_set = (const float*)d_in[1];   // [16,100] fp32
    float* out_mask = (float*)d_out;                  // [16,512,512]
    float* out_vs   = (float*)d_out + BATCH * NPIX;   // [16,100]

    const int threads = 256;
    const int blocks  = (HDIM / 32) * (WDIM / 32);    // 256
    fq_mask_kernel<<<blocks, threads, 0, stream>>>(value_set, out_mask, out_vs);
}

// Round 4
// 11.140 us; speedup vs baseline: 1.0782x; 1.0602x over previous
//
#include <hip/hip_runtime.h>
#include <math.h>

// Problem constants (reference: B=16, C=3, H=W=512, N_BINS=100)
#define HDIM   512
#define WDIM   512
#define BATCH  16
#define NBINS  100
#define NPIX   (HDIM * WDIM)
#define BG     4            // batches per block (batch-group size)

// max_radius = sqrt(512^2+512^2)/2 = 256*sqrt(2); step = max_radius/100
#define STEP      3.6203867196751236f
#define INV_STEP  0.27621358640099516f
#define CUT       8.0f      // sigmoid(-8)=3.35e-4; truncation err <= ~7e-4 << 2e-2

__device__ __forceinline__ float4 fma4(float a, float4 m, float4 c) {
    c.x = fmaf(a, m.x, c.x);
    c.y = fmaf(a, m.y, c.y);
    c.z = fmaf(a, m.z, c.z);
    c.w = fmaf(a, m.w, c.w);
    return c;
}

__global__ __launch_bounds__(256) void fq_mask_kernel(
    const float* __restrict__ value_set,  // [16][100]
    float* __restrict__ out_mask,         // [16][512][512]
    float* __restrict__ out_vs)           // [16][100] passthrough
{
    // Block = (batch-group bg of 4 batches) x (32x32 pixel tile).
    const int bg   = blockIdx.x >> 8;     // 0..3
    const int tile = blockIdx.x & 255;    // 0..255
    const int tid  = threadIdx.x;

    // Stage this group's value rows transposed: vst[r][j] = value_set[bg*4+j][r]
    __shared__ __align__(16) float vst[NBINS * BG];
    for (int i = tid; i < NBINS * BG; i += 256) {
        int r = i >> 2, j = i & 3;
        vst[i] = value_set[(bg * BG + j) * NBINS + r];
    }
    __syncthreads();

    // Wave = 8 rows x 32 cols; thread = 4 consecutive cols (float4 stores).
    const int lane   = tid & 63;
    const int wv     = tid >> 6;
    const int row_in = wv * 8 + (lane >> 3);
    const int col_in = (lane & 7) * 4;
    const int by = tile >> 4;
    const int bx = tile & 15;
    const int h  = by * 32 + row_in;
    const int w  = bx * 32 + col_in;

    const float fy  = (float)h - 256.0f;
    const float dy2 = fy * fy;
    float d[4];
    #pragma unroll
    for (int p = 0; p < 4; ++p) {
        float dx = (float)(w + p) - 256.0f;
        d[p] = sqrtf(dy2 + dx * dx);
    }
    const float dmin = fminf(fminf(d[0], d[1]), fminf(d[2], d[3]));
    const float dmax = fmaxf(fmaxf(d[0], d[1]), fmaxf(d[2], d[3]));
    int r_lo = (int)floorf((dmin - CUT) * INV_STEP); if (r_lo < 0) r_lo = 0;
    int r_hi = (int)floorf((dmax + CUT) * INV_STEP); if (r_hi > NBINS - 1) r_hi = NBINS - 1;
    const int cnt = r_hi - r_lo + 1;   // ~3-6 iterations

    // e_p = exp(dist_p - STEP*(r+1)); per bin: s = 1/(1+e), then e *= exp(-STEP).
    const float dec = __expf(-STEP);
    float e[4], sp[4];
    #pragma unroll
    for (int p = 0; p < 4; ++p) {
        e[p]  = __expf(d[p] - STEP * (float)(r_lo + 1));
        sp[p] = 0.0f;   // matches reference: mask 0 = s[0] - 0
    }

    float4 acc[BG];
    #pragma unroll
    for (int j = 0; j < BG; ++j) acc[j] = make_float4(0.f, 0.f, 0.f, 0.f);

    const float4* vr = (const float4*)vst;
    int r = r_lo;
    for (int i = 0; i < cnt; ++i, ++r) {
        float mm[4];
        #pragma unroll
        for (int p = 0; p < 4; ++p) {
            float s = __builtin_amdgcn_rcpf(1.0f + e[p]);  // sigmoid
            mm[p]  = s - sp[p];
            sp[p]  = s;
            e[p]  *= dec;
        }
        const float4 m = make_float4(mm[0], mm[1], mm[2], mm[3]);
        float4 v = vr[r];    // broadcast-ish: <=4 distinct consecutive rows/wave
        acc[0] = fma4(v.x, m, acc[0]);
        acc[1] = fma4(v.y, m, acc[1]);
        acc[2] = fma4(v.z, m, acc[2]);
        acc[3] = fma4(v.w, m, acc[3]);
    }

    const int pixbase = h * WDIM + w;
    #pragma unroll
    for (int j = 0; j < BG; ++j)
        *(float4*)&out_mask[(bg * BG + j) * NPIX + pixbase] = acc[j];

    // Output 1: value_set passthrough (d_out is poisoned -> must write).
    if (blockIdx.x == 0) {
        for (int i = tid; i < BATCH * NBINS; i += 256)
            out_vs[i] = value_set[i];
    }
}

extern "C" void kernel_launch(void* const* d_in, const int* in_sizes, int n_in,
                              void* d_out, int out_size, void* d_ws, size_t ws_size,
                              hipStream_t stream) {
    // d_in[0] = x [16,3,512,512] fp32 — UNUSED by the math (shape-only).
    const float* value_set = (const float*)d_in[1];   // [16,100] fp32
    float* out_mask = (float*)d_out;                  // [16,512,512]
    float* out_vs   = (float*)d_out + BATCH * NPIX;   // [16,100]

    const int threads = 256;
    const int blocks  = (BATCH / BG) * (HDIM / 32) * (WDIM / 32);  // 4 * 256 = 1024
    fq_mask_kernel<<<blocks, threads, 0, stream>>>(value_set, out_mask, out_vs);
}